// Round 1
// baseline (5887.562 us; speedup 1.0000x reference)
//
#include <hip/hip_runtime.h>

// Linear RNN: h_0 = initial + proj[0]; h_t = h_{t-1} @ Whh^T + proj[t-1], t=1..T-1
// out = (hidden, hidden) concatenated, hidden[n][t][j] fp32.
//
// R2: phase/ks were latency-bound (VALUBusy 17%, occ 11%): W-row reads had 8KB
// lane stride -> 64 cache lines per wave load, 1 wave/SIMD. Fix:
//  * transpose Whh / KS powers once (tr_kernel), inner loops read WT[k][j] contiguous
//  * thread layout nh=tid&15 (batch row in low bits) -> 16-way same-address merge
//    on W loads: exactly 1 MB/step/CU of L1 line traffic
//  * phase: 1024 thr/block (4 waves/SIMD), single padded h buffer [16][516] in LDS
//    (broadcast reads, 2-way-free banks), 2 barriers/step
//  * ks: 512 thr/block, 2 blocks/CU, transposed P
// Lifetimes: WhhT in first MB of G1 (dead except during KS; re-transposed before
// phase3). matsT in half-A tail below mats (dead until phase3 overwrites).
// Accumulation order unchanged -> bitwise-identical results to R1.

constexpr int NN = 16;
constexpr int TT = 4096;
constexpr int II = 256;
constexpr int HH = 512;
constexpr int CK = 16;                 // steps per chunk
constexpr int NC = 256;                // chunks
constexpr long NTH = (long)NN * TT * HH;   // 33,554,432 floats per output half
constexpr int NMATS = 11;              // W^2 .. W^2048
constexpr int HP = HH + 4;             // padded LDS row stride (bank-spread)

#define FMA8(hs, wa, wb) \
    acc0.x = fmaf(hs, wa.x, acc0.x); acc0.y = fmaf(hs, wa.y, acc0.y); \
    acc0.z = fmaf(hs, wa.z, acc0.z); acc0.w = fmaf(hs, wa.w, acc0.w); \
    acc1.x = fmaf(hs, wb.x, acc1.x); acc1.y = fmaf(hs, wb.y, acc1.y); \
    acc1.z = fmaf(hs, wb.z, acc1.z); acc1.w = fmaf(hs, wb.w, acc1.w);

// ---------------------------------------------------------------- proj ------
// B[n][t][j] = bi[j] + sum_i x[n][max(t-1,0)][i] * Wi[j][i]
// grid (TT/32, HH/128, NN), block 256
__global__ __launch_bounds__(256) void proj_kernel(
    const float* __restrict__ x, const float* __restrict__ Wi,
    const float* __restrict__ bi, float* __restrict__ Bh)
{
    const int t0 = blockIdx.x * 32;
    const int j0 = blockIdx.y * 128;
    const int n  = blockIdx.z;
    __shared__ __align__(16) float xs[32][II];   // 32 KB

    {   // stage 32 x-rows (with t-1 shift, clamped)
        const int r  = threadIdx.x >> 3;
        const int ci = threadIdx.x & 7;
        int s = t0 + r - 1; if (s < 0) s = 0;
        const float4* src = (const float4*)(x + ((size_t)n * TT + s) * II);
        float4* drow = (float4*)xs[r];
#pragma unroll
        for (int q = 0; q < 8; q++) drow[ci + 8 * q] = src[ci + 8 * q];
    }
    __syncthreads();

    const int tj  = threadIdx.x & 31;   // j-quad
    const int tt4 = threadIdx.x >> 5;   // t-quad (0..7)
    const int j   = j0 + tj * 4;

    float c0[4] = {0,0,0,0}, c1[4] = {0,0,0,0}, c2[4] = {0,0,0,0}, c3[4] = {0,0,0,0};
    for (int i = 0; i < II; i += 4) {
        float4 w0 = *(const float4*)(Wi + (size_t)(j + 0) * II + i);
        float4 w1 = *(const float4*)(Wi + (size_t)(j + 1) * II + i);
        float4 w2 = *(const float4*)(Wi + (size_t)(j + 2) * II + i);
        float4 w3 = *(const float4*)(Wi + (size_t)(j + 3) * II + i);
#pragma unroll
        for (int a = 0; a < 4; a++) {
            float4 xv = *(const float4*)(&xs[tt4 * 4 + a][i]);
            c0[a] = fmaf(xv.x, w0.x, c0[a]); c0[a] = fmaf(xv.y, w0.y, c0[a]);
            c0[a] = fmaf(xv.z, w0.z, c0[a]); c0[a] = fmaf(xv.w, w0.w, c0[a]);
            c1[a] = fmaf(xv.x, w1.x, c1[a]); c1[a] = fmaf(xv.y, w1.y, c1[a]);
            c1[a] = fmaf(xv.z, w1.z, c1[a]); c1[a] = fmaf(xv.w, w1.w, c1[a]);
            c2[a] = fmaf(xv.x, w2.x, c2[a]); c2[a] = fmaf(xv.y, w2.y, c2[a]);
            c2[a] = fmaf(xv.z, w2.z, c2[a]); c2[a] = fmaf(xv.w, w2.w, c2[a]);
            c3[a] = fmaf(xv.x, w3.x, c3[a]); c3[a] = fmaf(xv.y, w3.y, c3[a]);
            c3[a] = fmaf(xv.z, w3.z, c3[a]); c3[a] = fmaf(xv.w, w3.w, c3[a]);
        }
    }
    const float4 bv = *(const float4*)(bi + j);
#pragma unroll
    for (int a = 0; a < 4; a++) {
        const int t = t0 + tt4 * 4 + a;
        float4 o = make_float4(c0[a] + bv.x, c1[a] + bv.y, c2[a] + bv.z, c3[a] + bv.w);
        *(float4*)(Bh + ((size_t)n * TT + t) * HH + j) = o;
    }
}

// ----------------------------------------------------------- transpose ------
// dst = src^T for blockIdx.z-th 512x512 matrix (src/dst contiguous per z).
__global__ __launch_bounds__(256) void tr_kernel(
    const float* __restrict__ src, float* __restrict__ dst)
{
    __shared__ float tile[32][33];
    const size_t mo = (size_t)blockIdx.z * HH * HH;
    const int x0 = blockIdx.x * 32, y0 = blockIdx.y * 32;
    const int tx = threadIdx.x & 31, ty = threadIdx.x >> 5;   // ty 0..7
#pragma unroll
    for (int r = 0; r < 4; r++)
        tile[ty + 8 * r][tx] = src[mo + (size_t)(y0 + ty + 8 * r) * HH + (x0 + tx)];
    __syncthreads();
#pragma unroll
    for (int r = 0; r < 4; r++)
        dst[mo + (size_t)(x0 + ty + 8 * r) * HH + (y0 + tx)] = tile[tx][ty + 8 * r];
}

// ---------------------------------------------------------- phase 1 / 3 -----
// One block per chunk, 1024 threads: thread = (nh = tid&15 -> 1 batch row,
// jh = tid>>4 -> 8 cols). W loads: all 16 nh-lanes of a wave read the SAME
// WT[k][j..] address -> merged; per-CU W line traffic = 1 MB/step.
// h kept in single LDS buffer [16][516] (padded rows: broadcast reads, 2-way-free
// banks); two barriers per step (read-done, write-visible).
template <int PHASE>
__global__ __launch_bounds__(1024) void phase_kernel(
    const float* __restrict__ WT,     // Whh^T [k][j]
    float* __restrict__ Bh,           // half B (B values; phase3 overwrites with h)
    const float* __restrict__ init_,  // initial [N][H]
    const float* __restrict__ Gin,    // boundary states [NC][N][H]
    float* __restrict__ Zout,         // chunk-final local states [NC][N][H]
    float* __restrict__ outA)         // half A
{
    __shared__ __align__(16) float h[NN][HP];   // 33 KB
    const int c   = blockIdx.x;
    const int tid = threadIdx.x;
    const int nh  = tid & 15;
    const int j   = (tid >> 4) * 8;
    const size_t rowB = (size_t)nh * TT * HH;

    {   // init local state: one row, 8 cols per thread
        float4 a0, a1;
        if (c == 0) {
            float4 i0 = *(const float4*)(init_ + (size_t)nh * HH + j);
            float4 i1 = *(const float4*)(init_ + (size_t)nh * HH + j + 4);
            float4 b0 = *(const float4*)(Bh + rowB + j);
            float4 b1 = *(const float4*)(Bh + rowB + j + 4);
            a0 = make_float4(i0.x + b0.x, i0.y + b0.y, i0.z + b0.z, i0.w + b0.w);
            a1 = make_float4(i1.x + b1.x, i1.y + b1.y, i1.z + b1.z, i1.w + b1.w);
            if (PHASE == 3) {
                *(float4*)(outA + rowB + j)     = a0;
                *(float4*)(outA + rowB + j + 4) = a1;
                *(float4*)(Bh   + rowB + j)     = a0;
                *(float4*)(Bh   + rowB + j + 4) = a1;
            }
        } else if (PHASE == 1) {
            const int t0 = c * CK;
            a0 = *(const float4*)(Bh + rowB + (size_t)t0 * HH + j);
            a1 = *(const float4*)(Bh + rowB + (size_t)t0 * HH + j + 4);
        } else {
            const float* g = Gin + (size_t)(c - 1) * NN * HH + (size_t)nh * HH;
            a0 = *(const float4*)(g + j);
            a1 = *(const float4*)(g + j + 4);
        }
        *(float4*)(&h[nh][j])     = a0;
        *(float4*)(&h[nh][j + 4]) = a1;
    }
    __syncthreads();

    // PHASE 1: init value IS the local state at t0 -> loop from t0+1.
    // PHASE 3: init value is the state at t0-1 (true boundary) -> loop from t0.
    const int tstart = (PHASE == 1) ? (c * CK + 1) : ((c == 0) ? 1 : c * CK);
    const int tend   = c * CK + CK;

    for (int t = tstart; t < tend; t++) {
        float4 acc0 = make_float4(0.f, 0.f, 0.f, 0.f);
        float4 acc1 = make_float4(0.f, 0.f, 0.f, 0.f);
        // issue B addend early: latency hides under the k-loop
        float* bp = Bh + rowB + (size_t)t * HH + j;
        float4 b0 = *(const float4*)(bp);
        float4 b1 = *(const float4*)(bp + 4);

        const float* hr  = h[nh];
        const float* wpA = WT + j;            // rows k, k+1
        const float* wpB = WT + 2 * HH + j;   // rows k+2, k+3
#pragma unroll 2
        for (int k = 0; k < HH; k += 4) {
            float4 hv  = *(const float4*)(hr + k);
            float4 wa0 = *(const float4*)(wpA);
            float4 wb0 = *(const float4*)(wpA + 4);
            float4 wa1 = *(const float4*)(wpA + HH);
            float4 wb1 = *(const float4*)(wpA + HH + 4);
            float4 wa2 = *(const float4*)(wpB);
            float4 wb2 = *(const float4*)(wpB + 4);
            float4 wa3 = *(const float4*)(wpB + HH);
            float4 wb3 = *(const float4*)(wpB + HH + 4);
            FMA8(hv.x, wa0, wb0)
            FMA8(hv.y, wa1, wb1)
            FMA8(hv.z, wa2, wb2)
            FMA8(hv.w, wa3, wb3)
            wpA += 4 * HH;
            wpB += 4 * HH;
        }

        __syncthreads();   // all reads of h done
        float4 o0 = make_float4(acc0.x + b0.x, acc0.y + b0.y, acc0.z + b0.z, acc0.w + b0.w);
        float4 o1 = make_float4(acc1.x + b1.x, acc1.y + b1.y, acc1.z + b1.z, acc1.w + b1.w);
        *(float4*)(&h[nh][j])     = o0;
        *(float4*)(&h[nh][j + 4]) = o1;
        if (PHASE == 3) {
            float* op = outA + rowB + (size_t)t * HH + j;
            *(float4*)(op)     = o0;
            *(float4*)(op + 4) = o1;
            *(float4*)(bp)     = o0;
            *(float4*)(bp + 4) = o1;
        }
        __syncthreads();   // writes visible before next step's reads
    }

    if (PHASE == 1) {
        float* zp = Zout + (size_t)c * NN * HH + (size_t)nh * HH + j;
        *(float4*)(zp)     = *(const float4*)(&h[nh][j]);
        *(float4*)(zp + 4) = *(const float4*)(&h[nh][j + 4]);
    }
}

// ----------------------------------------------------------- squaring -------
// Out = A @ A, 512x512 row-major. grid (4, 32): 128-col slice x 16-row slice.
__global__ __launch_bounds__(256) void sq_kernel(
    const float* __restrict__ A, float* __restrict__ Out)
{
    const int j0 = blockIdx.x * 128;
    const int a0 = blockIdx.y * 16;
    __shared__ __align__(16) float As[16][HH];   // 32 KB
    {
        const float4* src = (const float4*)(A + (size_t)a0 * HH);
        float4* d = (float4*)As;
#pragma unroll
        for (int r = 0; r < 8; r++) d[threadIdx.x + r * 256] = src[threadIdx.x + r * 256];
    }
    __syncthreads();

    const int jh = threadIdx.x & 63;   // 64 col-pairs
    const int j  = j0 + jh * 2;
    const int r0 = (threadIdx.x >> 6) * 4;   // 4 rows each

    float ax[4] = {0,0,0,0}, ay[4] = {0,0,0,0};
    for (int k = 0; k < HH; k += 4) {
        float2 b0 = *(const float2*)(A + (size_t)(k + 0) * HH + j);
        float2 b1 = *(const float2*)(A + (size_t)(k + 1) * HH + j);
        float2 b2 = *(const float2*)(A + (size_t)(k + 2) * HH + j);
        float2 b3 = *(const float2*)(A + (size_t)(k + 3) * HH + j);
#pragma unroll
        for (int r = 0; r < 4; r++) {
            float4 av = *(const float4*)(&As[r0 + r][k]);
            ax[r] = fmaf(av.x, b0.x, ax[r]); ax[r] = fmaf(av.y, b1.x, ax[r]);
            ax[r] = fmaf(av.z, b2.x, ax[r]); ax[r] = fmaf(av.w, b3.x, ax[r]);
            ay[r] = fmaf(av.x, b0.y, ay[r]); ay[r] = fmaf(av.y, b1.y, ay[r]);
            ay[r] = fmaf(av.z, b2.y, ay[r]); ay[r] = fmaf(av.w, b3.y, ay[r]);
        }
    }
#pragma unroll
    for (int r = 0; r < 4; r++) {
        float2 o = make_float2(ax[r], ay[r]);
        *(float2*)(Out + (size_t)(a0 + r0 + r) * HH + j) = o;
    }
}

// --------------------------------------------------------- Kogge-Stone ------
// Gout[c] = Gin[c] + Gin[c-s] @ P^T  (PT = transposed power), copy for c < s.
// grid (2, NC): col-half x c. block 512 (2 blocks/CU, 16 waves/CU).
__global__ __launch_bounds__(512, 4) void ks_kernel(
    const float* __restrict__ Gin, float* __restrict__ Gout,
    const float* __restrict__ PT, int sft)
{
    const int c   = blockIdx.y;
    const int tid = threadIdx.x;
    const int j0  = blockIdx.x * 256;

    if (c < sft) {   // copy this col-slice
        const float4* src = (const float4*)(Gin + (size_t)c * NN * HH);
        float4* dst = (float4*)(Gout + (size_t)c * NN * HH);
#pragma unroll
        for (int r = 0; r < 2; r++) {
            int idx = tid + r * 512;          // 0..1023
            int n = idx >> 6, f = idx & 63;
            dst[n * 128 + (j0 >> 2) + f] = src[n * 128 + (j0 >> 2) + f];
        }
        return;
    }

    __shared__ __align__(16) float hs[NN][HP];   // 33 KB = Gin[c-sft], padded rows
    {
        const float4* src = (const float4*)(Gin + (size_t)(c - sft) * NN * HH);
#pragma unroll
        for (int r = 0; r < 4; r++) {
            int idx = tid + r * 512;          // 0..2047
            int n = idx >> 7, f = idx & 127;
            *(float4*)(&hs[n][f * 4]) = src[idx];
        }
    }
    __syncthreads();

    const int nh = tid & 15;
    const int j  = j0 + (tid >> 4) * 8;   // 32 jh-groups x 8 cols = 256
    const float* hr  = hs[nh];
    const float* wpA = PT + j;
    const float* wpB = PT + 2 * HH + j;
    float4 acc0 = make_float4(0.f, 0.f, 0.f, 0.f);
    float4 acc1 = make_float4(0.f, 0.f, 0.f, 0.f);
#pragma unroll 2
    for (int k = 0; k < HH; k += 4) {
        float4 hv  = *(const float4*)(hr + k);
        float4 wa0 = *(const float4*)(wpA);
        float4 wb0 = *(const float4*)(wpA + 4);
        float4 wa1 = *(const float4*)(wpA + HH);
        float4 wb1 = *(const float4*)(wpA + HH + 4);
        float4 wa2 = *(const float4*)(wpB);
        float4 wb2 = *(const float4*)(wpB + 4);
        float4 wa3 = *(const float4*)(wpB + HH);
        float4 wb3 = *(const float4*)(wpB + HH + 4);
        FMA8(hv.x, wa0, wb0)
        FMA8(hv.y, wa1, wb1)
        FMA8(hv.z, wa2, wb2)
        FMA8(hv.w, wa3, wb3)
        wpA += 4 * HH;
        wpB += 4 * HH;
    }

    const size_t base = (size_t)c * NN * HH + (size_t)nh * HH + j;
    float4 g0 = *(const float4*)(Gin + base);
    float4 g1 = *(const float4*)(Gin + base + 4);
    *(float4*)(Gout + base) =
        make_float4(g0.x + acc0.x, g0.y + acc0.y, g0.z + acc0.z, g0.w + acc0.w);
    *(float4*)(Gout + base + 4) =
        make_float4(g1.x + acc1.x, g1.y + acc1.y, g1.z + acc1.z, g1.w + acc1.w);
}

// ------------------------------------------------------------- launch -------
extern "C" void kernel_launch(void* const* d_in, const int* in_sizes, int n_in,
                              void* d_out, int out_size, void* d_ws, size_t ws_size,
                              hipStream_t stream)
{
    const float* x    = (const float*)d_in[0];
    const float* ini  = (const float*)d_in[1];
    const float* Wi   = (const float*)d_in[2];
    const float* bi   = (const float*)d_in[3];
    const float* Whh  = (const float*)d_in[4];
    float* out   = (float*)d_out;
    float* halfB = out + NTH;
    // W-powers + their transposes live in the tail of half A: read only before
    // phase 3, then overwritten by the final output. 11 + 8 = 19 MB.
    float* mats  = out + NTH - (long)NMATS * HH * HH;
    float* matsT = out + NTH - (long)(NMATS + 8) * HH * HH;
    // Kogge-Stone ping-pong buffers in workspace: 2 * 8 MB.
    float* G0 = (float*)d_ws;
    float* G1 = G0 + (size_t)NC * NN * HH;
    // WhhT lives in the first MB of G1: dead during phase1 (G1 unused until KS
    // round 0 writes it) and re-created after KS for phase3.

    // 0) shifted input projection -> half B
    proj_kernel<<<dim3(TT / 32, HH / 128, NN), 256, 0, stream>>>(x, Wi, bi, halfB);

    // 0b) WhhT -> G1 (for phase1)
    tr_kernel<<<dim3(16, 16, 1), 256, 0, stream>>>(Whh, G1);

    // 1) chunk-local scans -> z_c in G0
    phase_kernel<1><<<dim3(NC), 1024, 0, stream>>>(G1, halfB, ini, nullptr, G0, nullptr);

    // 2) powers W^2 .. W^2048
    sq_kernel<<<dim3(4, 32), 256, 0, stream>>>(Whh, mats);
    for (int i = 1; i < NMATS; i++)
        sq_kernel<<<dim3(4, 32), 256, 0, stream>>>(mats + (size_t)(i - 1) * HH * HH,
                                                   mats + (size_t)i * HH * HH);
    // 2b) transposed powers W^16 .. W^2048 for KS (mats[3..10] -> matsT[0..7])
    tr_kernel<<<dim3(16, 16, 8), 256, 0, stream>>>(mats + (size_t)3 * HH * HH, matsT);

    // 3) Kogge-Stone over 256 boundary states (round r uses (W^(16*2^r))^T)
    for (int r = 0; r < 8; r++) {
        const float* src = (r & 1) ? G1 : G0;
        float* dst       = (r & 1) ? G0 : G1;
        ks_kernel<<<dim3(2, NC), 512, 0, stream>>>(src, dst,
                                                   matsT + (size_t)r * HH * HH,
                                                   1 << r);
    }
    // after 8 rounds the result is back in G0

    // 3b) re-create WhhT in G1 (KS clobbered it; G1 dead from here on)
    tr_kernel<<<dim3(16, 16, 1), 256, 0, stream>>>(Whh, G1);

    // 4) chunk re-scan from true boundaries, write both halves
    phase_kernel<3><<<dim3(NC), 1024, 0, stream>>>(G1, halfB, ini, G0, nullptr, out);
}

// Round 3
// 2128.732 us; speedup vs baseline: 2.7658x; 2.7658x over previous
//
#include <hip/hip_runtime.h>

// Linear RNN: h_0 = initial + proj[0]; h_t = h_{t-1} @ Whh^T + proj[t-1], t=1..T-1
// out = (hidden, hidden) concatenated, hidden[n][t][j] fp32.
//
// R4 = R3 fixed: (a) FMA16 macro param renamed w->W_ (the `.w` member token was
// being macro-substituted -> compile error); (b) pipeline slots are now literal
// constants via explicit group-of-4 bodies (rule #20: runtime-indexed register
// arrays spill to scratch).
// Design: 4x4 register blocking (64 FMA / 8 load-insts), 4-deep register
// pipeline (launch_bounds(512,2) -> 256 VGPR budget), XOR-swizzled float4 LDS
// for h (broadcast reads on 4 disjoint bank-groups, 2-way-free writes),
// coalesced 256B W-runs 4-lane-merged. Ascending-k fmaf order -> numerics
// identical to R1/R2.

constexpr int NN = 16;
constexpr int TT = 4096;
constexpr int II = 256;
constexpr int HH = 512;
constexpr int CK = 16;                 // steps per chunk
constexpr int NC = 256;                // chunks
constexpr long NTH = (long)NN * TT * HH;   // floats per output half
constexpr int NMATS = 11;              // W^2 .. W^2048

__device__ __forceinline__ float4 ld4(const float* p) { return *(const float4*)p; }

// acc0..acc3 are float4 (4 cols) for 4 rows; e0..e3 are the rows' k-elements.
#define FMA16(W_, e0, e1, e2, e3) \
    acc0.x = fmaf(e0, (W_).x, acc0.x); acc0.y = fmaf(e0, (W_).y, acc0.y); \
    acc0.z = fmaf(e0, (W_).z, acc0.z); acc0.w = fmaf(e0, (W_).w, acc0.w); \
    acc1.x = fmaf(e1, (W_).x, acc1.x); acc1.y = fmaf(e1, (W_).y, acc1.y); \
    acc1.z = fmaf(e1, (W_).z, acc1.z); acc1.w = fmaf(e1, (W_).w, acc1.w); \
    acc2.x = fmaf(e2, (W_).x, acc2.x); acc2.y = fmaf(e2, (W_).y, acc2.y); \
    acc2.z = fmaf(e2, (W_).z, acc2.z); acc2.w = fmaf(e2, (W_).w, acc2.w); \
    acc3.x = fmaf(e3, (W_).x, acc3.x); acc3.y = fmaf(e3, (W_).y, acc3.y); \
    acc3.z = fmaf(e3, (W_).z, acc3.z); acc3.w = fmaf(e3, (W_).w, acc3.w);

// one k-quad: W rows k..k+3 (cols j..j+3), h rows n0..n0+3 (elems k..k+3)
#define COMPUTE(sl) \
    FMA16(wv##sl[0], hv##sl[0].x, hv##sl[1].x, hv##sl[2].x, hv##sl[3].x) \
    FMA16(wv##sl[1], hv##sl[0].y, hv##sl[1].y, hv##sl[2].y, hv##sl[3].y) \
    FMA16(wv##sl[2], hv##sl[0].z, hv##sl[1].z, hv##sl[2].z, hv##sl[3].z) \
    FMA16(wv##sl[3], hv##sl[0].w, hv##sl[1].w, hv##sl[2].w, hv##sl[3].w)

// prefetch quad kk into slot sl (phase/ks: W = WT, h = swizzled hs)
#define PRE_PH(sl, kk) { \
    const float* wp_ = WT + (size_t)(4 * (kk)) * HH + j; \
    wv##sl[0] = ld4(wp_);            wv##sl[1] = ld4(wp_ + HH); \
    wv##sl[2] = ld4(wp_ + 2 * HH);   wv##sl[3] = ld4(wp_ + 3 * HH); \
    hv##sl[0] = hs[hb0 + (((kk)) ^ sw0)]; hv##sl[1] = hs[hb1 + (((kk)) ^ sw0)]; \
    hv##sl[2] = hs[hb2 + (((kk)) ^ sw1)]; hv##sl[3] = hs[hb3 + (((kk)) ^ sw1)]; }

#define PIPE_DECL float4 wv0[4], wv1[4], wv2[4], wv3[4]; \
                  float4 hv0[4], hv1[4], hv2[4], hv3[4];

// ----------------------------------------------------------- transpose ------
// dst[C][R] = src[R][C]^T for blockIdx.z-th matrix. grid (C/32, R/32, nz).
__global__ __launch_bounds__(256) void trg_kernel(
    const float* __restrict__ src, float* __restrict__ dst, int R, int C)
{
    __shared__ float tile[32][33];
    const size_t mo = (size_t)blockIdx.z * R * C;
    const int x0 = blockIdx.x * 32, y0 = blockIdx.y * 32;
    const int tx = threadIdx.x & 31, ty = threadIdx.x >> 5;
#pragma unroll
    for (int r = 0; r < 4; r++)
        tile[ty + 8 * r][tx] = src[mo + (size_t)(y0 + ty + 8 * r) * C + (x0 + tx)];
    __syncthreads();
#pragma unroll
    for (int r = 0; r < 4; r++)
        dst[mo + (size_t)(x0 + ty + 8 * r) * R + (y0 + tx)] = tile[tx][ty + 8 * r];
}

// ---------------------------------------------------------------- proj ------
// B[n][t][j] = bi[j] + sum_i x[n][max(t-1,0)][i] * WiT[i][j]
// grid (TT/32, HH/128, NN), block 256. Thread: 4 t-rows x 4 j-cols.
__global__ __launch_bounds__(256) void proj_kernel(
    const float* __restrict__ x, const float* __restrict__ WiT,
    const float* __restrict__ bi, float* __restrict__ Bh)
{
    const int t0 = blockIdx.x * 32;
    const int j0 = blockIdx.y * 128;
    const int n  = blockIdx.z;
    // swizzled: x[t][i-quad q] at slot t*64 + (q ^ (t>>2)). 32 KB.
    __shared__ float4 xs[32 * 64];

    {   // stage 32 x-rows (with t-1 shift, clamped)
        const int r  = threadIdx.x >> 3;
        const int ci = threadIdx.x & 7;
        int s = t0 + r - 1; if (s < 0) s = 0;
        const float4* src = (const float4*)(x + ((size_t)n * TT + s) * II);
        const int rb = r * 64, rs = r >> 2;
#pragma unroll
        for (int q = 0; q < 8; q++) xs[rb + ((ci + 8 * q) ^ rs)] = src[ci + 8 * q];
    }
    __syncthreads();

    const int tj  = threadIdx.x & 31;
    const int tt4 = threadIdx.x >> 5;   // 0..7
    const int j   = j0 + tj * 4;
    const int xb0 = (tt4 * 4 + 0) * 64, xb1 = (tt4 * 4 + 1) * 64;
    const int xb2 = (tt4 * 4 + 2) * 64, xb3 = (tt4 * 4 + 3) * 64;
    const int swx = tt4;

    float4 acc0 = {0,0,0,0}, acc1 = {0,0,0,0}, acc2 = {0,0,0,0}, acc3 = {0,0,0,0};
    PIPE_DECL
#define PRE_PJ(sl, kk) { \
    const float* wp_ = WiT + (size_t)(4 * (kk)) * HH + j; \
    wv##sl[0] = ld4(wp_);            wv##sl[1] = ld4(wp_ + HH); \
    wv##sl[2] = ld4(wp_ + 2 * HH);   wv##sl[3] = ld4(wp_ + 3 * HH); \
    hv##sl[0] = xs[xb0 + (((kk)) ^ swx)]; hv##sl[1] = xs[xb1 + (((kk)) ^ swx)]; \
    hv##sl[2] = xs[xb2 + (((kk)) ^ swx)]; hv##sl[3] = xs[xb3 + (((kk)) ^ swx)]; }

    PRE_PJ(0, 0) PRE_PJ(1, 1) PRE_PJ(2, 2) PRE_PJ(3, 3)
    for (int g = 0; g < 15; g++) {          // kq = 4g .. 4g+3, computes 0..59
        const int kq = g * 4;
        COMPUTE(0) PRE_PJ(0, kq + 4)
        COMPUTE(1) PRE_PJ(1, kq + 5)
        COMPUTE(2) PRE_PJ(2, kq + 6)
        COMPUTE(3) PRE_PJ(3, kq + 7)
    }
    COMPUTE(0) COMPUTE(1) COMPUTE(2) COMPUTE(3)   // kq = 60..63

    const float4 bv = ld4(bi + j);
    {
        const int tb = t0 + tt4 * 4;
        *(float4*)(Bh + ((size_t)n * TT + tb + 0) * HH + j) =
            make_float4(acc0.x + bv.x, acc0.y + bv.y, acc0.z + bv.z, acc0.w + bv.w);
        *(float4*)(Bh + ((size_t)n * TT + tb + 1) * HH + j) =
            make_float4(acc1.x + bv.x, acc1.y + bv.y, acc1.z + bv.z, acc1.w + bv.w);
        *(float4*)(Bh + ((size_t)n * TT + tb + 2) * HH + j) =
            make_float4(acc2.x + bv.x, acc2.y + bv.y, acc2.z + bv.z, acc2.w + bv.w);
        *(float4*)(Bh + ((size_t)n * TT + tb + 3) * HH + j) =
            make_float4(acc3.x + bv.x, acc3.y + bv.y, acc3.z + bv.z, acc3.w + bv.w);
    }
}

// ---------------------------------------------------------- phase 1 / 3 -----
// One block/chunk, 512 threads: thread = (nq=tid&3 -> 4 rows, jq=tid>>2 -> 4 cols).
// h in swizzled LDS: h[n] quad kq at slot n*128 + (kq ^ (n>>1)).
// k-loop: 4-deep register pipeline; W loads coalesced 256B runs, 4-lane merged.
template <int PHASE>
__global__ __launch_bounds__(512, 2) void phase_kernel(
    const float* __restrict__ WT,     // Whh^T [k][j]
    float* __restrict__ Bh,           // half B (phase3 overwrites with h)
    const float* __restrict__ init_,  // initial [N][H]
    const float* __restrict__ Gin,    // boundary states [NC][N][H]
    float* __restrict__ Zout,         // chunk-final local states [NC][N][H]
    float* __restrict__ outA)         // half A
{
    __shared__ float4 hs[NN * 128];   // 32 KB
    const int c   = blockIdx.x;
    const int tid = threadIdx.x;
    const int nq  = tid & 3;
    const int n0  = nq * 4;
    const int jq  = tid >> 2;         // 0..127
    const int j   = jq * 4;
    const int hb0 = (n0 + 0) * 128, hb1 = (n0 + 1) * 128;
    const int hb2 = (n0 + 2) * 128, hb3 = (n0 + 3) * 128;
    const int sw0 = nq * 2, sw1 = nq * 2 + 1;

    {   // stage initial state: 4 rows x 1 float4
        float4 v[4];
        if (c == 0) {
#pragma unroll
            for (int rr = 0; rr < 4; rr++) {
                const int nn = n0 + rr;
                float4 iv = ld4(init_ + (size_t)nn * HH + j);
                float4 bv = ld4(Bh + (size_t)nn * TT * HH + j);
                v[rr] = make_float4(iv.x + bv.x, iv.y + bv.y, iv.z + bv.z, iv.w + bv.w);
                if (PHASE == 3) {
                    *(float4*)(outA + (size_t)nn * TT * HH + j) = v[rr];
                    *(float4*)(Bh   + (size_t)nn * TT * HH + j) = v[rr];
                }
            }
        } else if (PHASE == 1) {
            const int t0 = c * CK;
#pragma unroll
            for (int rr = 0; rr < 4; rr++)
                v[rr] = ld4(Bh + ((size_t)(n0 + rr) * TT + t0) * HH + j);
        } else {
#pragma unroll
            for (int rr = 0; rr < 4; rr++)
                v[rr] = ld4(Gin + (size_t)(c - 1) * NN * HH + (size_t)(n0 + rr) * HH + j);
        }
        hs[hb0 + (jq ^ sw0)] = v[0];
        hs[hb1 + (jq ^ sw0)] = v[1];
        hs[hb2 + (jq ^ sw1)] = v[2];
        hs[hb3 + (jq ^ sw1)] = v[3];
    }
    __syncthreads();

    // PHASE 1: init value IS the local state at t0 -> loop from t0+1.
    // PHASE 3: init value is the state at t0-1 (true boundary) -> loop from t0.
    const int tstart = (PHASE == 1) ? (c * CK + 1) : ((c == 0) ? 1 : c * CK);
    const int tend   = c * CK + CK;

    for (int t = tstart; t < tend; t++) {
        // issue B addends early: latency hides under the k-loop
        float* bp0 = Bh + ((size_t)(n0 + 0) * TT + t) * HH + j;
        float* bp1 = Bh + ((size_t)(n0 + 1) * TT + t) * HH + j;
        float* bp2 = Bh + ((size_t)(n0 + 2) * TT + t) * HH + j;
        float* bp3 = Bh + ((size_t)(n0 + 3) * TT + t) * HH + j;
        float4 b0 = ld4(bp0), b1 = ld4(bp1), b2 = ld4(bp2), b3 = ld4(bp3);

        float4 acc0 = {0,0,0,0}, acc1 = {0,0,0,0}, acc2 = {0,0,0,0}, acc3 = {0,0,0,0};
        PIPE_DECL
        PRE_PH(0, 0) PRE_PH(1, 1) PRE_PH(2, 2) PRE_PH(3, 3)
        for (int g = 0; g < 31; g++) {      // computes kq 0..123, prefetch 4..127
            const int kq = g * 4;
            COMPUTE(0) PRE_PH(0, kq + 4)
            COMPUTE(1) PRE_PH(1, kq + 5)
            COMPUTE(2) PRE_PH(2, kq + 6)
            COMPUTE(3) PRE_PH(3, kq + 7)
        }
        COMPUTE(0) COMPUTE(1) COMPUTE(2) COMPUTE(3)   // kq = 124..127

        float4 o0 = make_float4(acc0.x + b0.x, acc0.y + b0.y, acc0.z + b0.z, acc0.w + b0.w);
        float4 o1 = make_float4(acc1.x + b1.x, acc1.y + b1.y, acc1.z + b1.z, acc1.w + b1.w);
        float4 o2 = make_float4(acc2.x + b2.x, acc2.y + b2.y, acc2.z + b2.z, acc2.w + b2.w);
        float4 o3 = make_float4(acc3.x + b3.x, acc3.y + b3.y, acc3.z + b3.z, acc3.w + b3.w);

        __syncthreads();   // all reads of hs done
        hs[hb0 + (jq ^ sw0)] = o0;
        hs[hb1 + (jq ^ sw0)] = o1;
        hs[hb2 + (jq ^ sw1)] = o2;
        hs[hb3 + (jq ^ sw1)] = o3;
        if (PHASE == 3) {
            *(float4*)(outA + ((size_t)(n0 + 0) * TT + t) * HH + j) = o0;
            *(float4*)(outA + ((size_t)(n0 + 1) * TT + t) * HH + j) = o1;
            *(float4*)(outA + ((size_t)(n0 + 2) * TT + t) * HH + j) = o2;
            *(float4*)(outA + ((size_t)(n0 + 3) * TT + t) * HH + j) = o3;
            *(float4*)bp0 = o0; *(float4*)bp1 = o1;
            *(float4*)bp2 = o2; *(float4*)bp3 = o3;
        }
        __syncthreads();   // writes visible before next step's reads
    }

    if (PHASE == 1) {
        float* zp = Zout + (size_t)c * NN * HH;
        *(float4*)(zp + (size_t)(n0 + 0) * HH + j) = hs[hb0 + (jq ^ sw0)];
        *(float4*)(zp + (size_t)(n0 + 1) * HH + j) = hs[hb1 + (jq ^ sw0)];
        *(float4*)(zp + (size_t)(n0 + 2) * HH + j) = hs[hb2 + (jq ^ sw1)];
        *(float4*)(zp + (size_t)(n0 + 3) * HH + j) = hs[hb3 + (jq ^ sw1)];
    }
}

// ----------------------------------------------------------- squaring -------
// Out = A @ A, 512x512 row-major. grid (4, 32). Thread: 4 rows x 2 cols, pipelined.
__global__ __launch_bounds__(256) void sq_kernel(
    const float* __restrict__ A, float* __restrict__ Out)
{
    const int j0 = blockIdx.x * 128;
    const int a0 = blockIdx.y * 16;
    // swizzled: A[a0+r] quad q at slot r*128 + (q ^ (r>>2)). 32 KB.
    __shared__ float4 As[16 * 128];
    {
#pragma unroll
        for (int rr = 0; rr < 8; rr++) {
            int idx = threadIdx.x + rr * 256;      // 0..2047
            int row = idx >> 7, s = idx & 127;
            As[row * 128 + (s ^ (row >> 2))] = ld4(A + (size_t)(a0 + row) * HH + s * 4);
        }
    }
    __syncthreads();

    const int jh = threadIdx.x & 63;
    const int j  = j0 + jh * 2;
    const int rq = threadIdx.x >> 6;      // 0..3 (uniform per wave -> As broadcast)
    const int ab0 = (rq * 4 + 0) * 128, ab1 = (rq * 4 + 1) * 128;
    const int ab2 = (rq * 4 + 2) * 128, ab3 = (rq * 4 + 3) * 128;

    float2 bw0[4], bw1[4], bw2[4], bw3[4];
    float4 av0[4], av1[4], av2[4], av3[4];
    float2 c0 = {0,0}, c1 = {0,0}, c2 = {0,0}, c3 = {0,0};
#define SQ_PRE(sl, kk) { \
    const float* bp_ = A + (size_t)(4 * (kk)) * HH + j; \
    bw##sl[0] = *(const float2*)(bp_);            bw##sl[1] = *(const float2*)(bp_ + HH); \
    bw##sl[2] = *(const float2*)(bp_ + 2 * HH);   bw##sl[3] = *(const float2*)(bp_ + 3 * HH); \
    av##sl[0] = As[ab0 + (((kk)) ^ rq)]; av##sl[1] = As[ab1 + (((kk)) ^ rq)]; \
    av##sl[2] = As[ab2 + (((kk)) ^ rq)]; av##sl[3] = As[ab3 + (((kk)) ^ rq)]; }
#define SQ_F(Bv_, e0, e1, e2, e3) \
    c0.x = fmaf(e0, (Bv_).x, c0.x); c0.y = fmaf(e0, (Bv_).y, c0.y); \
    c1.x = fmaf(e1, (Bv_).x, c1.x); c1.y = fmaf(e1, (Bv_).y, c1.y); \
    c2.x = fmaf(e2, (Bv_).x, c2.x); c2.y = fmaf(e2, (Bv_).y, c2.y); \
    c3.x = fmaf(e3, (Bv_).x, c3.x); c3.y = fmaf(e3, (Bv_).y, c3.y);
#define SQ_C(sl) \
    SQ_F(bw##sl[0], av##sl[0].x, av##sl[1].x, av##sl[2].x, av##sl[3].x) \
    SQ_F(bw##sl[1], av##sl[0].y, av##sl[1].y, av##sl[2].y, av##sl[3].y) \
    SQ_F(bw##sl[2], av##sl[0].z, av##sl[1].z, av##sl[2].z, av##sl[3].z) \
    SQ_F(bw##sl[3], av##sl[0].w, av##sl[1].w, av##sl[2].w, av##sl[3].w)

    SQ_PRE(0, 0) SQ_PRE(1, 1) SQ_PRE(2, 2) SQ_PRE(3, 3)
    for (int g = 0; g < 31; g++) {
        const int kq = g * 4;
        SQ_C(0) SQ_PRE(0, kq + 4)
        SQ_C(1) SQ_PRE(1, kq + 5)
        SQ_C(2) SQ_PRE(2, kq + 6)
        SQ_C(3) SQ_PRE(3, kq + 7)
    }
    SQ_C(0) SQ_C(1) SQ_C(2) SQ_C(3)

    *(float2*)(Out + (size_t)(a0 + rq * 4 + 0) * HH + j) = c0;
    *(float2*)(Out + (size_t)(a0 + rq * 4 + 1) * HH + j) = c1;
    *(float2*)(Out + (size_t)(a0 + rq * 4 + 2) * HH + j) = c2;
    *(float2*)(Out + (size_t)(a0 + rq * 4 + 3) * HH + j) = c3;
}

// --------------------------------------------------------- Kogge-Stone ------
// Gout[c] = Gin[c] + Gin[c-s] @ P^T (WT = transposed power), copy for c < s.
// grid (NC), block 512: same tile/pipeline as phase step.
__global__ __launch_bounds__(512, 2) void ks_kernel(
    const float* __restrict__ Gin, float* __restrict__ Gout,
    const float* __restrict__ WT, int sft)
{
    __shared__ float4 hs[NN * 128];
    const int c   = blockIdx.x;
    const int tid = threadIdx.x;

    if (c < sft) {   // copy
        const float4* src = (const float4*)(Gin + (size_t)c * NN * HH);
        float4* dst = (float4*)(Gout + (size_t)c * NN * HH);
#pragma unroll
        for (int r = 0; r < 4; r++) dst[tid + r * 512] = src[tid + r * 512];
        return;
    }

    const int nq  = tid & 3;
    const int n0  = nq * 4;
    const int jq  = tid >> 2;
    const int j   = jq * 4;
    const int hb0 = (n0 + 0) * 128, hb1 = (n0 + 1) * 128;
    const int hb2 = (n0 + 2) * 128, hb3 = (n0 + 3) * 128;
    const int sw0 = nq * 2, sw1 = nq * 2 + 1;

    float4 g[4];
    {
        const float* sp = Gin + (size_t)(c - sft) * NN * HH;
        const float* gp = Gin + (size_t)c * NN * HH;
        float4 v[4];
#pragma unroll
        for (int rr = 0; rr < 4; rr++) {
            v[rr] = ld4(sp + (size_t)(n0 + rr) * HH + j);
            g[rr] = ld4(gp + (size_t)(n0 + rr) * HH + j);
        }
        hs[hb0 + (jq ^ sw0)] = v[0];
        hs[hb1 + (jq ^ sw0)] = v[1];
        hs[hb2 + (jq ^ sw1)] = v[2];
        hs[hb3 + (jq ^ sw1)] = v[3];
    }
    __syncthreads();

    float4 acc0 = {0,0,0,0}, acc1 = {0,0,0,0}, acc2 = {0,0,0,0}, acc3 = {0,0,0,0};
    PIPE_DECL
    PRE_PH(0, 0) PRE_PH(1, 1) PRE_PH(2, 2) PRE_PH(3, 3)
    for (int g2 = 0; g2 < 31; g2++) {
        const int kq = g2 * 4;
        COMPUTE(0) PRE_PH(0, kq + 4)
        COMPUTE(1) PRE_PH(1, kq + 5)
        COMPUTE(2) PRE_PH(2, kq + 6)
        COMPUTE(3) PRE_PH(3, kq + 7)
    }
    COMPUTE(0) COMPUTE(1) COMPUTE(2) COMPUTE(3)

    float* op = Gout + (size_t)c * NN * HH;
    *(float4*)(op + (size_t)(n0 + 0) * HH + j) =
        make_float4(g[0].x + acc0.x, g[0].y + acc0.y, g[0].z + acc0.z, g[0].w + acc0.w);
    *(float4*)(op + (size_t)(n0 + 1) * HH + j) =
        make_float4(g[1].x + acc1.x, g[1].y + acc1.y, g[1].z + acc1.z, g[1].w + acc1.w);
    *(float4*)(op + (size_t)(n0 + 2) * HH + j) =
        make_float4(g[2].x + acc2.x, g[2].y + acc2.y, g[2].z + acc2.z, g[2].w + acc2.w);
    *(float4*)(op + (size_t)(n0 + 3) * HH + j) =
        make_float4(g[3].x + acc3.x, g[3].y + acc3.y, g[3].z + acc3.z, g[3].w + acc3.w);
}

// ------------------------------------------------------------- launch -------
extern "C" void kernel_launch(void* const* d_in, const int* in_sizes, int n_in,
                              void* d_out, int out_size, void* d_ws, size_t ws_size,
                              hipStream_t stream)
{
    const float* x    = (const float*)d_in[0];
    const float* ini  = (const float*)d_in[1];
    const float* Wi   = (const float*)d_in[2];
    const float* bi   = (const float*)d_in[3];
    const float* Whh  = (const float*)d_in[4];
    float* out   = (float*)d_out;
    float* halfB = out + NTH;
    // Half-A tail scratch (dead until phase3 overwrites, reads all done before):
    // [WiT 0.5MB][matsT 8MB][mats 11MB]
    float* mats  = out + NTH - (long)NMATS * HH * HH;
    float* matsT = out + NTH - (long)(NMATS + 8) * HH * HH;
    float* WiT   = matsT - (long)II * HH;
    // Kogge-Stone ping-pong buffers in workspace: 2 * 8 MB.
    float* G0 = (float*)d_ws;
    float* G1 = G0 + (size_t)NC * NN * HH;
    // WhhT lives in G1 (dead during phase1; re-created after KS for phase3).

    // 0) WiT, shifted input projection -> half B
    trg_kernel<<<dim3(II / 32, HH / 32, 1), 256, 0, stream>>>(Wi, WiT, HH, II);
    proj_kernel<<<dim3(TT / 32, HH / 128, NN), 256, 0, stream>>>(x, WiT, bi, halfB);

    // 0b) WhhT -> G1 (for phase1)
    trg_kernel<<<dim3(16, 16, 1), 256, 0, stream>>>(Whh, G1, HH, HH);

    // 1) chunk-local scans -> z_c in G0
    phase_kernel<1><<<dim3(NC), 512, 0, stream>>>(G1, halfB, ini, nullptr, G0, nullptr);

    // 2) powers W^2 .. W^2048
    sq_kernel<<<dim3(4, 32), 256, 0, stream>>>(Whh, mats);
    for (int i = 1; i < NMATS; i++)
        sq_kernel<<<dim3(4, 32), 256, 0, stream>>>(mats + (size_t)(i - 1) * HH * HH,
                                                   mats + (size_t)i * HH * HH);
    // 2b) transposed powers W^16 .. W^2048 (mats[3..10] -> matsT[0..7])
    trg_kernel<<<dim3(16, 16, 8), 256, 0, stream>>>(mats + (size_t)3 * HH * HH, matsT,
                                                    HH, HH);

    // 3) Kogge-Stone over 256 boundary states (round r uses (W^(16*2^r))^T)
    for (int r = 0; r < 8; r++) {
        const float* src = (r & 1) ? G1 : G0;
        float* dst       = (r & 1) ? G0 : G1;
        ks_kernel<<<dim3(NC), 512, 0, stream>>>(src, dst,
                                                matsT + (size_t)r * HH * HH, 1 << r);
    }
    // after 8 rounds the result is back in G0

    // 3b) re-create WhhT in G1 (KS clobbered it; G1 dead from here on)
    trg_kernel<<<dim3(16, 16, 1), 256, 0, stream>>>(Whh, G1, HH, HH);

    // 4) chunk re-scan from true boundaries, write both halves
    phase_kernel<3><<<dim3(NC), 512, 0, stream>>>(G1, halfB, ini, G0, nullptr, out);
}